// Round 6
// baseline (338.901 us; speedup 1.0000x reference)
//
#include <hip/hip_runtime.h>
#include <stdint.h>

// CORDIV stochastic-computing divider — Round 6: global_load_lds staging.
//
// R1/R4/R5 all plateau at ~2.2 TB/s despite different codegen (VGPR 32/32/44):
// compiler-owned waitcnt placement keeps re-serializing register-level load
// batches, and per-iteration vmcnt(0) couples loads to store acks.
//
// Fix: async direct-to-LDS staging. Per chunk of 4 t-planes, each wave issues
// 8 global_load_lds (16B/lane, 1KB/wave-instr) into its own LDS slice —
// side-effecting intrinsics the compiler cannot sink, zero VGPR cost — then
// ONE `s_waitcnt vmcnt(0)`, then 4 compute+store steps from LDS.
// Waves only touch their own slice -> no __syncthreads anywhere.
// LDS 32KB/block -> 4-5 blocks/CU (~16-20 waves), each wave holds 8KB in
// flight during its wait -> ~130KB outstanding/CU >> ~6KB Little's-law need.

#define SC_T   16
#define SC_BUF 4
#define CHUNK  4
#define BLOCK  256

typedef float v4f __attribute__((ext_vector_type(4)));
typedef const __attribute__((address_space(1))) void glb_void;
typedef __attribute__((address_space(3))) void lds_void;

__global__ __launch_bounds__(BLOCK) void cordiv_kernel(
    const v4f* __restrict__ dividend,
    const v4f* __restrict__ divisor,
    const v4f* __restrict__ sr_init,
    const int* __restrict__ rng_table,
    v4f*       __restrict__ out,
    int n4)   // N / 4
{
    __shared__ v4f lds_dvd[CHUNK][BLOCK];
    __shared__ v4f lds_dvs[CHUNK][BLOCK];

    const int tid   = threadIdx.x;
    const int gid   = blockIdx.x * BLOCK + tid;
    const int wbase = tid & ~63;          // wave's first thread in block

    // rng table (uniform address -> scalar loads; values uniform per t)
    const int r0 = rng_table[0];
    const int r1 = rng_table[1];
    const int r2 = rng_table[2];
    const int r3 = rng_table[3];
    const int rtab[SC_BUF] = {r0, r1, r2, r3};

    v4f sr0 = sr_init[0 * n4 + gid];
    v4f sr1 = sr_init[1 * n4 + gid];
    v4f sr2 = sr_init[2 * n4 + gid];
    v4f sr3 = sr_init[3 * n4 + gid];

#pragma unroll
    for (int c = 0; c < SC_T / CHUNK; ++c) {
        // Stage chunk: 8 async 1KB direct-to-LDS loads, back-to-back.
        // gptr is lane-varying; LDS dest is wave-uniform base, HW deposits
        // lane l at base + l*16 -> lds[i][wbase + l] == lds[i][tid].
#pragma unroll
        for (int i = 0; i < CHUNK; ++i) {
            const int t = c * CHUNK + i;
            __builtin_amdgcn_global_load_lds(
                (glb_void*)(dividend + (size_t)t * n4 + gid),
                (lds_void*)&lds_dvd[i][wbase], 16, 0, 0);
            __builtin_amdgcn_global_load_lds(
                (glb_void*)(divisor + (size_t)t * n4 + gid),
                (lds_void*)&lds_dvs[i][wbase], 16, 0, 0);
        }

        // One drain for the whole batch (also drains prior chunk's stores).
        asm volatile("s_waitcnt vmcnt(0)" ::: "memory");

        // Compute + store the 4 staged planes.
#pragma unroll
        for (int i = 0; i < CHUNK; ++i) {
            const int t = c * CHUNK + i;
            const int r = rtab[t & (SC_BUF - 1)];   // constant-folded per t

            const v4f dvd = lds_dvd[i][tid];   // ds_read_b128, conflict-free
            const v4f dvs = lds_dvs[i][tid];

            const v4f hq = (r == 0) ? sr0 : (r == 1) ? sr1
                         : (r == 2) ? sr2 : sr3;

            v4f q;
            q.x = (dvs.x == 1.0f) ? dvd.x : hq.x;
            q.y = (dvs.y == 1.0f) ? dvd.y : hq.y;
            q.z = (dvs.z == 1.0f) ? dvd.z : hq.z;
            q.w = (dvs.w == 1.0f) ? dvd.w : hq.w;

            out[(size_t)t * n4 + gid] = q;

            sr3 = sr2; sr2 = sr1; sr1 = sr0; sr0 = q;
        }
    }
}

extern "C" void kernel_launch(void* const* d_in, const int* in_sizes, int n_in,
                              void* d_out, int out_size, void* d_ws, size_t ws_size,
                              hipStream_t stream) {
    const float* dividend = (const float*)d_in[0];   // [T, N]
    const float* divisor  = (const float*)d_in[1];   // [T, N]
    const float* sr_init  = (const float*)d_in[2];   // [BUF_DEP, N]
    const int*   rng      = (const int*)d_in[3];     // [4]
    float*       out      = (float*)d_out;           // [T, N]

    const int n  = in_sizes[0] / SC_T;   // N
    const int n4 = n / 4;                // N = 2^21, divisible by 4

    const int grid = (n4 + BLOCK - 1) / BLOCK;       // exact: 2048 blocks

    cordiv_kernel<<<grid, BLOCK, 0, stream>>>(
        (const v4f*)dividend, (const v4f*)divisor,
        (const v4f*)sr_init, rng, (v4f*)out, n4);
}

// Round 7
// 335.829 us; speedup vs baseline: 1.0091x; 1.0091x over previous
//
#include <hip/hip_runtime.h>
#include <stdint.h>

// CORDIV stochastic-computing divider — Round 7: hand-scheduled VMEM pipeline.
//
// R1/R4/R5/R6 all plateau at ~2.2 TB/s HBM (~3.3 TB/s incl. L3 hits) while
// m13's float4 copy does 6.3 TB/s on the same chip -> not a chip ceiling.
// Common flaw: compiler-owned (or vmcnt(0)) waits expose a full load-return
// latency per chunk per wave, and bursts are 1KB/stream before hopping 8MB.
//
// This round:
//  - Loads are raw `asm volatile(global_load_dwordx4)` — invisible to the
//    compiler's waitcnt bookkeeping; cannot be sunk/re-serialized.
//  - Exact `s_waitcnt vmcnt(N)` per (fully unrolled) t-step, N counted so
//    2 planes of loads (8 x 1KB) stay in flight at all times; stores are
//    NEVER waited on (vmcnt never 0 mid-loop).
//  - Each thread owns 2 lane-contiguous float4 groups -> 2KB contiguous
//    burst per stream per wave (better DRAM row locality).
//  - Steady state: 8KB in flight/wave x ~16 waves/CU = ~128KB/CU.

#define SC_T    16
#define D_AHEAD 2

typedef float v4f __attribute__((ext_vector_type(4)));

__device__ __forceinline__ v4f gload(const v4f* __restrict__ p) {
    v4f r;
    asm volatile("global_load_dwordx4 %0, %1, off" : "=v"(r) : "v"(p));
    return r;
}

// Wait until at most N VMEM ops outstanding; ties plane-t's 4 values so
// consumers can't hoist above the wait and the loads can't sink below it.
#define PIN_WAIT(N, a, b, c, d)                                          \
    asm volatile("s_waitcnt vmcnt(%c4)"                                  \
                 : "+v"(a), "+v"(b), "+v"(c), "+v"(d) : "i"(N) : "memory")

// Ops younger than plane-t's loads at its wait point:
// stores of planes t-2,t-1 (2 each) + loads of planes t+1,t+2 (4 each).
#define WAITN(t) (2 * ((t) >= 1) + 2 * ((t) >= 2) + \
                  4 * ((t) + 1 < SC_T) + 4 * ((t) + 2 < SC_T))

__global__ __launch_bounds__(256) void cordiv_kernel(
    const v4f* __restrict__ dividend,
    const v4f* __restrict__ divisor,
    const v4f* __restrict__ sr_init,
    const int* __restrict__ rng_table,
    v4f*       __restrict__ out,
    int n4)   // N / 4  (= 524288; grid covers it exactly)
{
    const int tid = threadIdx.x;
    const int g0  = blockIdx.x * 512 + tid;   // first float4 group
    const int g1  = g0 + 256;                 // second float4 group

    const int r0 = rng_table[0];
    const int r1 = rng_table[1];
    const int r2 = rng_table[2];
    const int r3 = rng_table[3];
    const int rtab[4] = {r0, r1, r2, r3};

    // Two independent shift registers (one per owned lane group).
    v4f srA0 = sr_init[0 * n4 + g0], srA1 = sr_init[1 * n4 + g0],
        srA2 = sr_init[2 * n4 + g0], srA3 = sr_init[3 * n4 + g0];
    v4f srB0 = sr_init[0 * n4 + g1], srB1 = sr_init[1 * n4 + g1],
        srB2 = sr_init[2 * n4 + g1], srB3 = sr_init[3 * n4 + g1];
    // Force the compiler's wait for its own sr loads HERE, before any of our
    // invisible asm loads enter the VMEM FIFO (it would emit vmcnt(0)).
    asm volatile("" : "+v"(srA0), "+v"(srA1), "+v"(srA2), "+v"(srA3),
                      "+v"(srB0), "+v"(srB1), "+v"(srB2), "+v"(srB3));

    // 3 rotating plane buffers (cur, +1 in flight, +2 in flight).
    v4f bD[3][2], bS[3][2];

#define ISSUE(t) do {                                                     \
        const int s_ = (t) % 3;                                           \
        bD[s_][0] = gload(dividend + (size_t)(t) * n4 + g0);              \
        bD[s_][1] = gload(dividend + (size_t)(t) * n4 + g1);              \
        bS[s_][0] = gload(divisor  + (size_t)(t) * n4 + g0);              \
        bS[s_][1] = gload(divisor  + (size_t)(t) * n4 + g1);              \
    } while (0)

#define STEP(t) do {                                                      \
        if ((t) + D_AHEAD < SC_T) ISSUE((t) + D_AHEAD);                   \
        const int s_ = (t) % 3;                                           \
        PIN_WAIT(WAITN(t), bD[s_][0], bD[s_][1], bS[s_][0], bS[s_][1]);   \
        const int r_ = rtab[(t) & 3];                                     \
        const v4f hqA = (r_ == 0) ? srA0 : (r_ == 1) ? srA1               \
                      : (r_ == 2) ? srA2 : srA3;                          \
        const v4f hqB = (r_ == 0) ? srB0 : (r_ == 1) ? srB1               \
                      : (r_ == 2) ? srB2 : srB3;                          \
        v4f qA, qB;                                                       \
        qA.x = (bS[s_][0].x == 1.0f) ? bD[s_][0].x : hqA.x;               \
        qA.y = (bS[s_][0].y == 1.0f) ? bD[s_][0].y : hqA.y;               \
        qA.z = (bS[s_][0].z == 1.0f) ? bD[s_][0].z : hqA.z;               \
        qA.w = (bS[s_][0].w == 1.0f) ? bD[s_][0].w : hqA.w;               \
        qB.x = (bS[s_][1].x == 1.0f) ? bD[s_][1].x : hqB.x;               \
        qB.y = (bS[s_][1].y == 1.0f) ? bD[s_][1].y : hqB.y;               \
        qB.z = (bS[s_][1].z == 1.0f) ? bD[s_][1].z : hqB.z;               \
        qB.w = (bS[s_][1].w == 1.0f) ? bD[s_][1].w : hqB.w;               \
        out[(size_t)(t) * n4 + g0] = qA;                                  \
        out[(size_t)(t) * n4 + g1] = qB;                                  \
        srA3 = srA2; srA2 = srA1; srA1 = srA0; srA0 = qA;                 \
        srB3 = srB2; srB2 = srB1; srB1 = srB0; srB0 = qB;                 \
    } while (0)

    // Prologue: 2 planes in flight before the first wait.
    ISSUE(0);
    ISSUE(1);

    STEP(0);  STEP(1);  STEP(2);  STEP(3);
    STEP(4);  STEP(5);  STEP(6);  STEP(7);
    STEP(8);  STEP(9);  STEP(10); STEP(11);
    STEP(12); STEP(13); STEP(14); STEP(15);

#undef STEP
#undef ISSUE
}

extern "C" void kernel_launch(void* const* d_in, const int* in_sizes, int n_in,
                              void* d_out, int out_size, void* d_ws, size_t ws_size,
                              hipStream_t stream) {
    const float* dividend = (const float*)d_in[0];   // [T, N]
    const float* divisor  = (const float*)d_in[1];   // [T, N]
    const float* sr_init  = (const float*)d_in[2];   // [BUF_DEP, N]
    const int*   rng      = (const int*)d_in[3];     // [4]
    float*       out      = (float*)d_out;           // [T, N]

    const int n  = in_sizes[0] / SC_T;   // N = 2^21
    const int n4 = n / 4;                // 524288, divisible by 512

    const int block = 256;
    const int grid  = n4 / 512;          // 1024 blocks, exact coverage

    cordiv_kernel<<<grid, block, 0, stream>>>(
        (const v4f*)dividend, (const v4f*)divisor,
        (const v4f*)sr_init, rng, (v4f*)out, n4);
}